// Round 1
// baseline (876.909 us; speedup 1.0000x reference)
//
#include <hip/hip_runtime.h>
#include <hip/hip_bf16.h>
#include <stdint.h>

// DCLS2d: B=16, Cin=Cout=128, H=W=112, KH=KW=3, DIL=4, D=9, PAD=4
//
// Stage 1 (build_K): dense K (Cout,Cin,9,9) bf16, GEMM-ready 4KB slabs:
//   elem(tap,o,c) at ((tap*8+c/16)*2+(c/8)%2)*1024 + o*8 + (c%8) [ushort].
// Stage 2 (dcls_conv): 81 tap-shifted GEMM accumulations, MFMA 32x32x16_bf16,
//   Cin reduced in chunks of 16 (cc loop).
//
// R6 change: K A-fragments are read DIRECTLY from global (L2-resident, 2.65MB)
// into registers with a distance-1 tap prefetch, instead of the LDS double-
// buffer + global_load_lds DMA + per-group "vmcnt(3); s_barrier" machinery.
// Rationale (rocprof R5): LDS read pipe at 6x ds_read_b128 per 8 MFMA was
// ~240us of LDS pipe vs 212us of matrix pipe (co-limiting), and ~430 barriers
// per block serialized 4-wave lockstep with only 2 blocks/CU resident.
// Now: 4 ds_read_b128 per 8 MFMA (sX only, ~160us pipe), 2 barriers per cc
// (16 total), K traffic 4.2GB from L2 (~120us VMEM pipe, overlapped).

typedef __attribute__((ext_vector_type(8))) short short8;
typedef __attribute__((ext_vector_type(16))) float f32x16;

__device__ inline unsigned short f2bf(float f) {
    union { float f; unsigned int u; } v; v.f = f;
    unsigned int u = v.u;
    return (unsigned short)((u + 0x7FFFu + ((u >> 16) & 1u)) >> 16); // RNE
}

__global__ void build_K(const float* __restrict__ weight,
                        const float* __restrict__ P,
                        unsigned short* __restrict__ Kws) {
    __shared__ float sacc[128 * 81];           // [c][tap], one o per block
    int tid = threadIdx.x;                     // 128 threads
    int o = blockIdx.x;
    int c = tid;
    float* a = &sacc[c * 81];
    for (int i = 0; i < 81; ++i) a[i] = 0.0f;
    int base = (o * 128 + c) * 9;
    #pragma unroll
    for (int kh = 0; kh < 3; ++kh) {
        #pragma unroll
        for (int kw = 0; kw < 3; ++kw) {
            int kk = kh * 3 + kw;
            float w  = weight[base + kk];
            float p0 = P[base + kk];
            float p1 = P[128 * 128 * 9 + base + kk];
            float ph = fminf(fmaxf((float)(kh * 4) + p0, 0.0f), 8.0f);
            float pw = fminf(fmaxf((float)(kw * 4) + p1, 0.0f), 8.0f);
            float fh = floorf(ph), fw = floorf(pw);
            float rh = ph - fh, rw = pw - fw;
            int ih = (int)fh, iw = (int)fw;
            int ih1 = min(ih + 1, 8), iw1 = min(iw + 1, 8);
            a[ih  * 9 + iw ] += w * (1.0f - rh) * (1.0f - rw);
            a[ih1 * 9 + iw ] += w * rh * (1.0f - rw);
            a[ih  * 9 + iw1] += w * (1.0f - rh) * rw;
            a[ih1 * 9 + iw1] += w * rh * rw;
        }
    }
    __syncthreads();
    // 1296 16B units per block (tap, chunk, half)
    for (int u = tid; u < 1296; u += 128) {
        int tap = u >> 4;
        int rem = u & 15;
        int chunk = rem >> 1, half = rem & 1;
        int c0 = chunk * 16 + half * 8;
        short8 v;
        #pragma unroll
        for (int j = 0; j < 8; ++j)
            v[j] = (short)f2bf(sacc[(c0 + j) * 81 + tap]);
        *(short8*)(Kws + ((tap * 8 + chunk) * 2 + half) * 1024 + o * 8) = v;
    }
}

// LDS: sX 18432 only (x window, per cc). No K staging.
__global__ __launch_bounds__(256, 2)
void dcls_conv(const float* __restrict__ x,
               const unsigned short* __restrict__ Kws,
               const float* __restrict__ bias,
               float* __restrict__ out) {
    __shared__ __align__(16) char sX[18432];

    int bid = blockIdx.x;             // 784 = 16 * 7 * 7
    int b   = bid / 49;
    int rem = bid % 49;
    int ty  = rem / 7, tx = rem % 7;
    int y0  = ty * 16, x0 = tx * 16;

    int tid  = threadIdx.x;
    int lane = tid & 63;
    int wave = tid >> 6;
    int mgrp = wave >> 1;             // m-tiles {2m, 2m+1}
    int ngrp = wave & 1;              // n-tiles {4n..4n+3}
    int half = lane >> 5;             // c-half within 16-chunk
    int l31  = lane & 31;
    int lrow = (lane >> 4) & 1;
    int lcol = lane & 15;

    f32x16 acc[2][4];
    #pragma unroll
    for (int i = 0; i < 2; ++i)
        #pragma unroll
        for (int j = 0; j < 4; ++j)
            #pragma unroll
            for (int k = 0; k < 16; ++k) acc[i][j][k] = 0.0f;

    int preA[2];                      // byte offsets within a 4KB slab
    #pragma unroll
    for (int i = 0; i < 2; ++i)
        preA[i] = half * 2048 + ((mgrp * 2 + i) * 32 + l31) * 16;
    int preB[4];                      // byte offsets into sX
    #pragma unroll
    for (int j = 0; j < 4; ++j)
        preB[j] = (2 * (ngrp * 4 + j) + lrow) * 768 + half * 384 + lcol * 16;

    const char* __restrict__ Kb = (const char*)Kws;

    for (int cc = 0; cc < 8; ++cc) {
        __syncthreads();              // all waves done reading prev sX
        // ---- stage x window (fp32 -> bf16), 1152 16B units ----
        {
            int cbase = cc * 16;
            #pragma unroll
            for (int it = 0; it < 5; ++it) {
                int u = tid + it * 256;
                if (u < 1152) {
                    int r  = u / 48;
                    int rr = u % 48;
                    int hf = rr / 24;
                    int co = rr % 24;
                    int h = y0 - 4 + r;
                    int w = x0 - 4 + co;
                    bool ok = (h >= 0) & (h < 112) & (w >= 0) & (w < 112);
                    const float* xp = x + (((b * 128 + cbase + hf * 8) * 112 + h) * 112 + w);
                    short8 v;
                    #pragma unroll
                    for (int j = 0; j < 8; ++j) {
                        float f = ok ? xp[j * 112 * 112] : 0.0f;
                        v[j] = (short)f2bf(f);
                    }
                    *(short8*)(sX + u * 16) = v;
                }
            }
        }
        __syncthreads();              // sX visible

        // ---- 81 taps, K A-frags straight from global (L2), prefetch dist 1 ----
        const char* Kc = Kb + (cc << 12);           // slab stride per tap = 32768
        short8 ca0 = *(const short8*)(Kc + preA[0]);            // tap 0
        short8 ca1 = *(const short8*)(Kc + preA[1]);
        for (int tg = 0; tg < 9; ++tg) {
            const char* Krow = Kc + (size_t)tg * (9 * 32768);
            int rowoff = tg * 768;
            #pragma unroll
            for (int t = 0; t < 9; ++t) {
                // prefetch next tap ((t+1)==9 lands naturally on next row's tap 0)
                const char* nx = Krow + (size_t)(t + 1) * 32768;
                if (t == 8 && tg == 8) nx = Krow + (size_t)8 * 32768; // clamp (dummy)
                short8 na0 = *(const short8*)(nx + preA[0]);
                short8 na1 = *(const short8*)(nx + preA[1]);

                int tapoff = rowoff + t * 16;
                short8 b0 = *(const short8*)(sX + preB[0] + tapoff);
                short8 b1 = *(const short8*)(sX + preB[1] + tapoff);
                short8 b2 = *(const short8*)(sX + preB[2] + tapoff);
                short8 b3 = *(const short8*)(sX + preB[3] + tapoff);

                acc[0][0] = __builtin_amdgcn_mfma_f32_32x32x16_bf16(ca0, b0, acc[0][0], 0, 0, 0);
                acc[1][0] = __builtin_amdgcn_mfma_f32_32x32x16_bf16(ca1, b0, acc[1][0], 0, 0, 0);
                acc[0][1] = __builtin_amdgcn_mfma_f32_32x32x16_bf16(ca0, b1, acc[0][1], 0, 0, 0);
                acc[1][1] = __builtin_amdgcn_mfma_f32_32x32x16_bf16(ca1, b1, acc[1][1], 0, 0, 0);
                acc[0][2] = __builtin_amdgcn_mfma_f32_32x32x16_bf16(ca0, b2, acc[0][2], 0, 0, 0);
                acc[1][2] = __builtin_amdgcn_mfma_f32_32x32x16_bf16(ca1, b2, acc[1][2], 0, 0, 0);
                acc[0][3] = __builtin_amdgcn_mfma_f32_32x32x16_bf16(ca0, b3, acc[0][3], 0, 0, 0);
                acc[1][3] = __builtin_amdgcn_mfma_f32_32x32x16_bf16(ca1, b3, acc[1][3], 0, 0, 0);

                ca0 = na0;            // forces vmcnt wait AFTER this tap's MFMAs
                ca1 = na1;
            }
        }
    }

    // ---- epilogue: C/D layout col=lane&31, row=(r&3)+8*(r>>2)+4*half ----
    #pragma unroll
    for (int i = 0; i < 2; ++i) {
        int ob = (mgrp * 2 + i) * 32;
        #pragma unroll
        for (int r = 0; r < 16; ++r) {
            int o = ob + (r & 3) + 8 * (r >> 2) + 4 * half;
            float bv = bias[o];
            #pragma unroll
            for (int j = 0; j < 4; ++j) {
                int nt  = ngrp * 4 + j;
                int row = y0 + 2 * nt + lrow;
                int col = x0 + lcol;
                out[((b * 128 + o) * 112 + row) * 112 + col] = acc[i][j][r] + bv;
            }
        }
    }
}

extern "C" void kernel_launch(void* const* d_in, const int* in_sizes, int n_in,
                              void* d_out, int out_size, void* d_ws, size_t ws_size,
                              hipStream_t stream) {
    const float* x      = (const float*)d_in[0];
    const float* weight = (const float*)d_in[1];
    const float* P      = (const float*)d_in[2];
    const float* bias   = (const float*)d_in[3];
    float* out = (float*)d_out;
    unsigned short* Kws = (unsigned short*)d_ws;   // 81*128*128 bf16 = 2.65 MB

    build_K<<<128, 128, 0, stream>>>(weight, P, Kws);
    dcls_conv<<<784, 256, 0, stream>>>(x, Kws, bias, out);
}

// Round 3
// 601.082 us; speedup vs baseline: 1.4589x; 1.4589x over previous
//
#include <hip/hip_runtime.h>
#include <hip/hip_bf16.h>
#include <stdint.h>

// DCLS2d: B=16, Cin=Cout=128, H=W=112, KH=KW=3, DIL=4, D=9, PAD=4
//
// Stage 1 (build_K): dense K (Cout,Cin,9,9) bf16, GEMM-ready 4KB slabs:
//   elem(tap,o,c) at ((tap*8+c/16)*2+(c/8)%2)*1024 + o*8 + (c%8) [ushort].
// Stage 2 (dcls_conv): 81 tap-shifted GEMM accumulations, MFMA 32x32x16_bf16,
//   Cin reduced in chunks of 16 (cc loop).
//
// R8 = R7 with the short4 name clash fixed (HIP defines short4; use s16x4).
// R7 design = R5 structure (global_load_lds K-DMA pipeline, which the R6
// regression proved necessary: direct global->reg K reads at prefetch
// distance 1 exposed L2 latency, MfmaUtil 46.7->28.4) plus two stall removals:
//  1. sK TRIPLE buffer: DMA for group g+2 is issued at the TOP of group g
//     (right after the barrier, which proves group g-1's readers are done) so
//     the second per-group barrier of R5 is deleted: 1 barrier/group, 216
//     fewer barriers/block, and 2 full compute-groups of DMA flight time.
//  2. sX staging for cc+1 is overlapped with cc's compute (T14 async-split):
//     3 uniform batches of 12 clamp-addressed global loads (issued at groups
//     3/12/21, converted at 6/15/24, hidden under MFMA), ds_write at cc end.
//     vmcnt immediates are statically recounted per group (vmcnt(15) where a
//     12-load batch sits in the FIFO between DMA groups). Loads are never
//     exec-skipped (clamped addresses + late mask) so per-wave vmcnt counts
//     stay uniform. Last cc stages (dead) channel-0 data: one code path.
// LDS: sX 18432 + 3 x 12288 sK = 55296.

typedef __attribute__((ext_vector_type(8))) short short8;
typedef __attribute__((ext_vector_type(4))) short s16x4;
typedef __attribute__((ext_vector_type(16))) float f32x16;

__device__ inline unsigned short f2bf(float f) {
    union { float f; unsigned int u; } v; v.f = f;
    unsigned int u = v.u;
    return (unsigned short)((u + 0x7FFFu + ((u >> 16) & 1u)) >> 16); // RNE
}

__global__ void build_K(const float* __restrict__ weight,
                        const float* __restrict__ P,
                        unsigned short* __restrict__ Kws) {
    __shared__ float sacc[128 * 81];           // [c][tap], one o per block
    int tid = threadIdx.x;                     // 128 threads
    int o = blockIdx.x;
    int c = tid;
    float* a = &sacc[c * 81];
    for (int i = 0; i < 81; ++i) a[i] = 0.0f;
    int base = (o * 128 + c) * 9;
    #pragma unroll
    for (int kh = 0; kh < 3; ++kh) {
        #pragma unroll
        for (int kw = 0; kw < 3; ++kw) {
            int kk = kh * 3 + kw;
            float w  = weight[base + kk];
            float p0 = P[base + kk];
            float p1 = P[128 * 128 * 9 + base + kk];
            float ph = fminf(fmaxf((float)(kh * 4) + p0, 0.0f), 8.0f);
            float pw = fminf(fmaxf((float)(kw * 4) + p1, 0.0f), 8.0f);
            float fh = floorf(ph), fw = floorf(pw);
            float rh = ph - fh, rw = pw - fw;
            int ih = (int)fh, iw = (int)fw;
            int ih1 = min(ih + 1, 8), iw1 = min(iw + 1, 8);
            a[ih  * 9 + iw ] += w * (1.0f - rh) * (1.0f - rw);
            a[ih1 * 9 + iw ] += w * rh * (1.0f - rw);
            a[ih  * 9 + iw1] += w * (1.0f - rh) * rw;
            a[ih1 * 9 + iw1] += w * rh * rw;
        }
    }
    __syncthreads();
    // 1296 16B units per block (tap, chunk, half)
    for (int u = tid; u < 1296; u += 128) {
        int tap = u >> 4;
        int rem = u & 15;
        int chunk = rem >> 1, half = rem & 1;
        int c0 = chunk * 16 + half * 8;
        short8 v;
        #pragma unroll
        for (int j = 0; j < 8; ++j)
            v[j] = (short)f2bf(sacc[(c0 + j) * 81 + tap]);
        *(short8*)(Kws + ((tap * 8 + chunk) * 2 + half) * 1024 + o * 8) = v;
    }
}

__device__ __forceinline__ void dma3g(const char* Kc, char* dst, int h,
                                      int woff, int lane16) {
    // 3 slabs of 4KB for taps 3h..3h+2; wave covers its 1KB quarter of each.
    const char* src = Kc + (size_t)(3 * h) * 32768 + woff + lane16;
    #pragma unroll
    for (int j = 0; j < 3; ++j)
        __builtin_amdgcn_global_load_lds(
            (const __attribute__((address_space(1))) char*)(src + (size_t)j * 32768),
            (__attribute__((address_space(3))) char*)(dst + j * 4096 + woff),
            16, 0, 0);
}

__global__ __launch_bounds__(256, 2)
void dcls_conv(const float* __restrict__ x,
               const unsigned short* __restrict__ Kws,
               const float* __restrict__ bias,
               float* __restrict__ out) {
    __shared__ __align__(16) char sX[18432];
    __shared__ __align__(16) char sK0[12288];
    __shared__ __align__(16) char sK1[12288];
    __shared__ __align__(16) char sK2[12288];

    int bid = blockIdx.x;             // 784 = 16 * 7 * 7
    int b   = bid / 49;
    int rem = bid % 49;
    int ty  = rem / 7, tx = rem % 7;
    int y0  = ty * 16, x0 = tx * 16;

    int tid  = threadIdx.x;
    int lane = tid & 63;
    int wave = tid >> 6;
    int mgrp = wave >> 1;             // m-tiles {2m, 2m+1}
    int ngrp = wave & 1;              // n-tiles {4n..4n+3}
    int half = lane >> 5;             // c-half within 16-chunk
    int l31  = lane & 31;
    int lrow = (lane >> 4) & 1;
    int lcol = lane & 15;
    int woff = wave * 1024;           // DMA wave quarter
    int lane16 = lane * 16;

    f32x16 acc[2][4];
    #pragma unroll
    for (int i = 0; i < 2; ++i)
        #pragma unroll
        for (int j = 0; j < 4; ++j)
            #pragma unroll
            for (int k = 0; k < 16; ++k) acc[i][j][k] = 0.0f;

    int preA0 = half * 2048 + ((mgrp * 2 + 0) * 32 + l31) * 16;
    int preA1 = half * 2048 + ((mgrp * 2 + 1) * 32 + l31) * 16;
    int preB[4];                      // byte offsets into sX
    #pragma unroll
    for (int j = 0; j < 4; ++j)
        preB[j] = (2 * (ngrp * 4 + j) + lrow) * 768 + half * 384 + lcol * 16;

    const char* __restrict__ Kb = (const char*)Kws;

    // ---- initial sX stage for cc=0 (serialized once per block) ----
    {
        #pragma unroll
        for (int it = 0; it < 5; ++it) {
            int u = tid + it * 256;
            if (u < 1152) {
                int r  = u / 48;
                int rr = u % 48;
                int hf = rr / 24;
                int co = rr % 24;
                int h = y0 - 4 + r;
                int w = x0 - 4 + co;
                bool ok = (h >= 0) & (h < 112) & (w >= 0) & (w < 112);
                const float* xp = x + ((b * 128 + hf * 8) * 12544 + h * 112 + w);
                short8 v;
                #pragma unroll
                for (int j = 0; j < 8; ++j) {
                    float f = ok ? xp[j * 12544] : 0.0f;
                    v[j] = (short)f2bf(f);
                }
                *(short8*)(sX + u * 16) = v;
            }
        }
    }
    __syncthreads();

#define KBUF(i) ((i) == 0 ? sK0 : (i) == 1 ? sK1 : sK2)

// Per-group: wait (counted) + barrier; issue DMA g+2; maybe issue/convert a
// staging batch; compute 3 taps. vmcnt table (verified by FIFO walk):
//   batches of 12 loads issued at g=3,12,21 sit in the FIFO -> g+1,g+2 use
//   vmcnt(15); g+3 (=6,15,24) uses vmcnt(3) which also drains the batch.
#define GRP(G) do {                                                          \
    if ((G) == 26)                                                           \
        asm volatile("s_waitcnt vmcnt(0)\n\ts_barrier" ::: "memory");        \
    else if ((G)==4||(G)==5||(G)==13||(G)==14||(G)==22||(G)==23)             \
        asm volatile("s_waitcnt vmcnt(15)\n\ts_barrier" ::: "memory");       \
    else                                                                     \
        asm volatile("s_waitcnt vmcnt(3)\n\ts_barrier" ::: "memory");        \
    if ((G) <= 24) dma3g(Kc, KBUF(((G) + 2) % 3), (G) + 2, woff, lane16);    \
    if ((G) == 3 || (G) == 12 || (G) == 21) {                                \
        const int bi_ = (G) / 9;                                             \
        _Pragma("unroll")                                                    \
        for (int i2 = 0; i2 < 3; ++i2) {                                     \
            int q_ = 3 * bi_ + i2;                                           \
            int V_ = q_ * 128 + (tid >> 1);                                  \
            int hp_ = tid & 1;                                               \
            int r_ = V_ / 48, rr_ = V_ % 48;                                 \
            int hf_ = rr_ / 24, co_ = rr_ % 24;                              \
            int h_ = y0 - 4 + r_, w_ = x0 - 4 + co_;                         \
            int hc_ = min(max(h_, 0), 111), wc_ = min(max(w_, 0), 111);      \
            okm[i2] = (h_ >= 0) & (h_ < 112) & (w_ >= 0) & (w_ < 112);       \
            const float* xp_ = x + ((b * 128 + nb + hf_ * 8 + hp_ * 4) * 12544 \
                                    + hc_ * 112 + wc_);                      \
            _Pragma("unroll")                                                \
            for (int j2 = 0; j2 < 4; ++j2)                                   \
                raw[i2 * 4 + j2] = xp_[j2 * 12544];                          \
        }                                                                    \
    }                                                                        \
    if ((G) == 6 || (G) == 15 || (G) == 24) {                                \
        const int bi_ = (G) / 9;                                             \
        _Pragma("unroll")                                                    \
        for (int i2 = 0; i2 < 3; ++i2) {                                     \
            s16x4 v_;                                                        \
            _Pragma("unroll")                                                \
            for (int j2 = 0; j2 < 4; ++j2) {                                 \
                float f_ = okm[i2] ? raw[i2 * 4 + j2] : 0.0f;                \
                v_[j2] = (short)f2bf(f_);                                    \
            }                                                                \
            stg[3 * bi_ + i2] = v_;                                          \
        }                                                                    \
    }                                                                        \
    {                                                                        \
        const char* kb_ = KBUF((G) % 3);                                     \
        _Pragma("unroll")                                                    \
        for (int j = 0; j < 3; ++j) {                                        \
            int tap_ = 3 * (G) + j;                                          \
            int tapoff_ = (tap_ / 9) * 768 + (tap_ % 9) * 16;                \
            short8 af0 = *(const short8*)(kb_ + j * 4096 + preA0);           \
            short8 af1 = *(const short8*)(kb_ + j * 4096 + preA1);           \
            short8 b0 = *(const short8*)(sX + preB[0] + tapoff_);            \
            short8 b1 = *(const short8*)(sX + preB[1] + tapoff_);            \
            short8 b2 = *(const short8*)(sX + preB[2] + tapoff_);            \
            short8 b3 = *(const short8*)(sX + preB[3] + tapoff_);            \
            acc[0][0] = __builtin_amdgcn_mfma_f32_32x32x16_bf16(af0, b0, acc[0][0], 0, 0, 0); \
            acc[1][0] = __builtin_amdgcn_mfma_f32_32x32x16_bf16(af1, b0, acc[1][0], 0, 0, 0); \
            acc[0][1] = __builtin_amdgcn_mfma_f32_32x32x16_bf16(af0, b1, acc[0][1], 0, 0, 0); \
            acc[1][1] = __builtin_amdgcn_mfma_f32_32x32x16_bf16(af1, b1, acc[1][1], 0, 0, 0); \
            acc[0][2] = __builtin_amdgcn_mfma_f32_32x32x16_bf16(af0, b2, acc[0][2], 0, 0, 0); \
            acc[1][2] = __builtin_amdgcn_mfma_f32_32x32x16_bf16(af1, b2, acc[1][2], 0, 0, 0); \
            acc[0][3] = __builtin_amdgcn_mfma_f32_32x32x16_bf16(af0, b3, acc[0][3], 0, 0, 0); \
            acc[1][3] = __builtin_amdgcn_mfma_f32_32x32x16_bf16(af1, b3, acc[1][3], 0, 0, 0); \
        }                                                                    \
    }                                                                        \
} while (0)

    for (int cc = 0; cc < 8; ++cc) {
        const char* Kc = Kb + (cc << 12);
        int nb = ((cc + 1) & 7) << 4;    // next-cc channel base (wraps; cc=7 dead)
        float raw[12];
        s16x4 stg[9];
        int okm[3];

        dma3g(Kc, sK0, 0, woff, lane16);   // G0
        dma3g(Kc, sK1, 1, woff, lane16);   // G1

        GRP(0);  GRP(1);  GRP(2);  GRP(3);  GRP(4);  GRP(5);  GRP(6);
        GRP(7);  GRP(8);  GRP(9);  GRP(10); GRP(11); GRP(12); GRP(13);
        GRP(14); GRP(15); GRP(16); GRP(17); GRP(18); GRP(19); GRP(20);
        GRP(21); GRP(22); GRP(23); GRP(24); GRP(25); GRP(26);

        // all waves finished reading sX (per-wave reads consumed; barrier syncs)
        asm volatile("s_barrier" ::: "memory");
        #pragma unroll
        for (int q = 0; q < 9; ++q)
            *(s16x4*)(sX + q * 2048 + tid * 8) = stg[q];
        __syncthreads();                   // writes visible; counters drained
    }

#undef GRP
#undef KBUF

    // ---- epilogue: C/D layout col=lane&31, row=(r&3)+8*(r>>2)+4*half ----
    #pragma unroll
    for (int i = 0; i < 2; ++i) {
        int ob = (mgrp * 2 + i) * 32;
        #pragma unroll
        for (int r = 0; r < 16; ++r) {
            int o = ob + (r & 3) + 8 * (r >> 2) + 4 * half;
            float bv = bias[o];
            #pragma unroll
            for (int j = 0; j < 4; ++j) {
                int nt  = ngrp * 4 + j;
                int row = y0 + 2 * nt + lrow;
                int col = x0 + lcol;
                out[((b * 128 + o) * 112 + row) * 112 + col] = acc[i][j][r] + bv;
            }
        }
    }
}

extern "C" void kernel_launch(void* const* d_in, const int* in_sizes, int n_in,
                              void* d_out, int out_size, void* d_ws, size_t ws_size,
                              hipStream_t stream) {
    const float* x      = (const float*)d_in[0];
    const float* weight = (const float*)d_in[1];
    const float* P      = (const float*)d_in[2];
    const float* bias   = (const float*)d_in[3];
    float* out = (float*)d_out;
    unsigned short* Kws = (unsigned short*)d_ws;   // 81*128*128 bf16 = 2.65 MB

    build_K<<<128, 128, 0, stream>>>(weight, P, Kws);
    dcls_conv<<<784, 256, 0, stream>>>(x, Kws, bias, out);
}